// Round 1
// 808.543 us; speedup vs baseline: 1.7610x; 1.7610x over previous
//
#include <hip/hip_runtime.h>
#include <stdint.h>

#define V_N 100000
#define E_N 50000
#define C_N 128

typedef unsigned short u16;
typedef unsigned int u32;

// ---------- bf16 helpers ----------
__device__ __forceinline__ u16 f2bf(float f) {
    union { float f; u32 i; } c; c.f = f;
    u32 i = c.i;
    i += 0x7fffu + ((i >> 16) & 1u);   // RNE
    return (u16)(i >> 16);
}
__device__ __forceinline__ void unpack2(u32 u, float& lo, float& hi) {
    union { u32 i; float f; } a, b;
    a.i = u << 16; b.i = u & 0xffff0000u;
    lo = a.f; hi = b.f;
}

__global__ __launch_bounds__(64) void flagf_k(float* out, float v) {
    if (threadIdx.x == 0 && blockIdx.x == 0) out[0] = v;
}

__global__ __launch_bounds__(256) void zero_i4(int4* __restrict__ p, int n) {
    int i = blockIdx.x * 256 + threadIdx.x;
    if (i < n) { int4 z = {0, 0, 0, 0}; p[i] = z; }
}

// ---------- histogram (int) ----------
__global__ __launch_bounds__(256) void hist_k(const int* __restrict__ v_ids,
                                              const int* __restrict__ e_ids,
                                              int* __restrict__ icnt_e,
                                              int* __restrict__ icnt_v, int nnz) {
    int i = blockIdx.x * 256 + threadIdx.x;
    if (i < nnz) {
        int e = e_ids[i], v = v_ids[i];
        if ((unsigned)e < (unsigned)E_N && (unsigned)v < (unsigned)V_N) {
            atomicAdd(icnt_e + e, 1);
            atomicAdd(icnt_v + v, 1);
        }
    }
}

// ---------- hierarchical exclusive scan: 147 blocks of 1024 elems ----------
#define NBLK_E 49
#define NBLK_V 98
#define NBLK_T (NBLK_E + NBLK_V)

__global__ __launch_bounds__(256) void scan_part_k(const int* __restrict__ icnt_e,
                                                   const int* __restrict__ icnt_v,
                                                   int* __restrict__ part) {
    int b = blockIdx.x;
    const int* cnt; int n; int rb;
    if (b < NBLK_E) { cnt = icnt_e; n = E_N; rb = b; }
    else            { cnt = icnt_v; n = V_N; rb = b - NBLK_E; }
    int i = rb * 1024 + threadIdx.x * 4;
    int s = 0;
    if (i + 3 < n) { int4 q = *(const int4*)(cnt + i); s = q.x + q.y + q.z + q.w; }
    else { for (int j = 0; j < 4; ++j) if (i + j < n) s += cnt[i + j]; }
    for (int d = 32; d; d >>= 1) s += __shfl_down(s, d);
    __shared__ int ws[4];
    if ((threadIdx.x & 63) == 0) ws[threadIdx.x >> 6] = s;
    __syncthreads();
    if (threadIdx.x == 0) part[b] = ws[0] + ws[1] + ws[2] + ws[3];
}

__global__ __launch_bounds__(256) void scan_carry_k(int* __restrict__ part,
                                                    int* __restrict__ off_e,
                                                    int* __restrict__ off_v) {
    __shared__ int s[NBLK_T];
    int t = threadIdx.x;
    if (t < NBLK_T) s[t] = part[t];
    __syncthreads();
    if (t == 0) {
        int run = 0;
        for (int j = 0; j < NBLK_E; ++j) { int x = s[j]; s[j] = run; run += x; }
        off_e[E_N] = run;
    } else if (t == 64) {
        int run = 0;
        for (int j = NBLK_E; j < NBLK_T; ++j) { int x = s[j]; s[j] = run; run += x; }
        off_v[V_N] = run;
    }
    __syncthreads();
    if (t < NBLK_T) part[t] = s[t];
}

__global__ __launch_bounds__(256) void scan_add_k(const int* __restrict__ icnt_e,
                                                  const int* __restrict__ icnt_v,
                                                  const int* __restrict__ part,
                                                  int* __restrict__ off_e, int* __restrict__ cur_e,
                                                  int* __restrict__ off_v, int* __restrict__ cur_v) {
    int b = blockIdx.x;
    const int* cnt; int n; int rb; int* off; int* cur;
    if (b < NBLK_E) { cnt = icnt_e; n = E_N; rb = b;           off = off_e; cur = cur_e; }
    else            { cnt = icnt_v; n = V_N; rb = b - NBLK_E;  off = off_v; cur = cur_v; }
    int tid = threadIdx.x, lane = tid & 63, wid = tid >> 6;
    int i = rb * 1024 + tid * 4;
    int x0 = 0, x1 = 0, x2 = 0, x3 = 0;
    if (i + 3 < n) { int4 q = *(const int4*)(cnt + i); x0 = q.x; x1 = q.y; x2 = q.z; x3 = q.w; }
    else {
        if (i     < n) x0 = cnt[i];
        if (i + 1 < n) x1 = cnt[i + 1];
        if (i + 2 < n) x2 = cnt[i + 2];
    }
    int ts = x0 + x1 + x2 + x3;
    int incl = ts;
    for (int d = 1; d < 64; d <<= 1) { int u = __shfl_up(incl, d); if (lane >= d) incl += u; }
    int texcl = incl - ts;
    __shared__ int wsum[4];
    if (lane == 63) wsum[wid] = incl;
    __syncthreads();
    int carry = part[b];
    for (int w2 = 0; w2 < wid; ++w2) carry += wsum[w2];
    int base = carry + texcl;
    int e0 = base, e1 = base + x0, e2 = e1 + x1, e3 = e2 + x2;
    if (i + 3 < n) {
        int4 o = { e0, e1, e2, e3 };
        *(int4*)(off + i) = o;
        *(int4*)(cur + i) = o;
    } else {
        if (i     < n) { off[i]     = e0; cur[i]     = e0; }
        if (i + 1 < n) { off[i + 1] = e1; cur[i + 1] = e1; }
        if (i + 2 < n) { off[i + 2] = e2; cur[i + 2] = e2; }
    }
}

// ---------- fill CSR adjacency (order within segment nondeterministic; sums commute) ----------
__global__ __launch_bounds__(256) void fill_k(const int* __restrict__ v_ids,
                                              const int* __restrict__ e_ids,
                                              int* __restrict__ cur_e, int* __restrict__ cur_v,
                                              int* __restrict__ se_src, int* __restrict__ sv_src,
                                              int nnz) {
    int i = blockIdx.x * 256 + threadIdx.x;
    if (i < nnz) {
        int e = e_ids[i], v = v_ids[i];
        if ((unsigned)e < (unsigned)E_N && (unsigned)v < (unsigned)V_N) {
            int pe = atomicAdd(cur_e + e, 1); se_src[pe] = v;
            int pv = atomicAdd(cur_v + v, 1); sv_src[pv] = e;
        }
    }
}

// ---------- tiled GEMM: C[m][n] = bf16( post( sum_k pre(A[m][k])*W[k][n] ) + b[n] ) ----------
// MODE 0: pre=id, post=id (gemm1).  MODE 1: pre=relu, post=*1/max(len,1) (gemm2).
// BM=128, N=128, BK=32. 256 threads, 8x8 outputs/thread.
// A-tile chunk-XOR swizzle breaks the ty-stride bank conflict; n-split (4tx | 64+4tx)
// keeps W reads at the free 2-way aliasing.
template<int MODE>
__global__ __launch_bounds__(256) void gemm_tiled_k(const float* __restrict__ A,
                                                    const float* __restrict__ W,
                                                    const float* __restrict__ bias,
                                                    const int* __restrict__ off,
                                                    u16* __restrict__ Cout, int M) {
    __shared__ float As[128 * 32];   // float4-chunk swizzled
    __shared__ float Wsh[32 * 128];
    const int tid = threadIdx.x;
    const int tx = tid & 15;     // n-group
    const int ty = tid >> 4;     // m-group (0..15)
    const int m0 = blockIdx.x * 128;

    float acc[8][8];
    #pragma unroll
    for (int i = 0; i < 8; ++i)
        #pragma unroll
        for (int j = 0; j < 8; ++j) acc[i][j] = 0.f;

    for (int kk = 0; kk < 128; kk += 32) {
        __syncthreads();
        // stage A: 128 rows x 32 cols (1024 float4s, 4 per thread)
        #pragma unroll
        for (int u = 0; u < 4; ++u) {
            int f = tid + u * 256;
            int r = f >> 3, c4 = f & 7;
            float4 val = { 0.f, 0.f, 0.f, 0.f };
            if (m0 + r < M) {
                val = *(const float4*)(A + (size_t)(m0 + r) * C_N + kk + c4 * 4);
                if (MODE) {
                    val.x = fmaxf(val.x, 0.f); val.y = fmaxf(val.y, 0.f);
                    val.z = fmaxf(val.z, 0.f); val.w = fmaxf(val.w, 0.f);
                }
            }
            int sc4 = c4 ^ ((r >> 3) & 7);
            *(float4*)(As + r * 32 + sc4 * 4) = val;
        }
        // stage W: 32 rows x 128 cols
        #pragma unroll
        for (int u = 0; u < 4; ++u) {
            int f = tid + u * 256;
            int r = f >> 5, c4 = f & 31;
            *(float4*)(Wsh + r * 128 + c4 * 4) = *(const float4*)(W + (size_t)(kk + r) * C_N + c4 * 4);
        }
        __syncthreads();
        #pragma unroll
        for (int k4 = 0; k4 < 32; k4 += 4) {
            float4 a[8];
            #pragma unroll
            for (int i = 0; i < 8; ++i) {
                int row = ty * 8 + i;                    // row>>3 == ty
                int sc4 = (k4 >> 2) ^ (ty & 7);
                a[i] = *(const float4*)(As + row * 32 + sc4 * 4);
            }
            #pragma unroll
            for (int dk = 0; dk < 4; ++dk) {
                float4 w0 = *(const float4*)(Wsh + (k4 + dk) * 128 + tx * 4);
                float4 w1 = *(const float4*)(Wsh + (k4 + dk) * 128 + 64 + tx * 4);
                #pragma unroll
                for (int i = 0; i < 8; ++i) {
                    float av = (dk == 0) ? a[i].x : (dk == 1) ? a[i].y : (dk == 2) ? a[i].z : a[i].w;
                    acc[i][0] = fmaf(av, w0.x, acc[i][0]);
                    acc[i][1] = fmaf(av, w0.y, acc[i][1]);
                    acc[i][2] = fmaf(av, w0.z, acc[i][2]);
                    acc[i][3] = fmaf(av, w0.w, acc[i][3]);
                    acc[i][4] = fmaf(av, w1.x, acc[i][4]);
                    acc[i][5] = fmaf(av, w1.y, acc[i][5]);
                    acc[i][6] = fmaf(av, w1.z, acc[i][6]);
                    acc[i][7] = fmaf(av, w1.w, acc[i][7]);
                }
            }
        }
    }

    float4 bb0 = *(const float4*)(bias + tx * 4);
    float4 bb1 = *(const float4*)(bias + 64 + tx * 4);
    #pragma unroll
    for (int i = 0; i < 8; ++i) {
        int m = m0 + ty * 8 + i;
        if (m >= M) break;
        float inv = 1.f;
        if (MODE) { int len = off[m + 1] - off[m]; inv = 1.f / (float)max(len, 1); }
        float v0, v1, v2, v3, v4, v5, v6, v7;
        if (MODE) {
            v0 = acc[i][0] * inv + bb0.x; v1 = acc[i][1] * inv + bb0.y;
            v2 = acc[i][2] * inv + bb0.z; v3 = acc[i][3] * inv + bb0.w;
            v4 = acc[i][4] * inv + bb1.x; v5 = acc[i][5] * inv + bb1.y;
            v6 = acc[i][6] * inv + bb1.z; v7 = acc[i][7] * inv + bb1.w;
        } else {
            v0 = acc[i][0] + bb0.x; v1 = acc[i][1] + bb0.y;
            v2 = acc[i][2] + bb0.z; v3 = acc[i][3] + bb0.w;
            v4 = acc[i][4] + bb1.x; v5 = acc[i][5] + bb1.y;
            v6 = acc[i][6] + bb1.z; v7 = acc[i][7] + bb1.w;
        }
        u32 p0 = (u32)f2bf(v0) | ((u32)f2bf(v1) << 16);
        u32 p1 = (u32)f2bf(v2) | ((u32)f2bf(v3) << 16);
        u32 p2 = (u32)f2bf(v4) | ((u32)f2bf(v5) << 16);
        u32 p3 = (u32)f2bf(v6) | ((u32)f2bf(v7) << 16);
        u32* dst = (u32*)(Cout + (size_t)m * C_N);
        uint2 q0 = { p0, p1 }, q1 = { p2, p3 };
        *(uint2*)(dst + tx * 2) = q0;
        *(uint2*)(dst + 32 + tx * 2) = q1;
    }
}

// ---------- seg_e: Ysum[e][c] = sum over segment of Xp[src][c]  (1 wave per edge) ----------
__global__ __launch_bounds__(256) void seg_e_k(const u16* __restrict__ Xp,
                                               const int* __restrict__ off,
                                               const int* __restrict__ srcs,
                                               float* __restrict__ Ysum, int E) {
    int e = blockIdx.x * 4 + (threadIdx.x >> 6);
    if (e >= E) return;
    int lane = threadIdx.x & 63;
    int j0 = off[e], j1 = off[e + 1];
    float a0 = 0.f, a1 = 0.f;
    int j = j0;
    for (; j + 1 < j1; j += 2) {
        int s0 = srcs[j], s1 = srcs[j + 1];
        u32 q0 = ((const u32*)(Xp + (size_t)s0 * C_N))[lane];
        u32 q1 = ((const u32*)(Xp + (size_t)s1 * C_N))[lane];
        float l0, h0, l1, h1;
        unpack2(q0, l0, h0); unpack2(q1, l1, h1);
        a0 += l0 + l1; a1 += h0 + h1;
    }
    if (j < j1) {
        int s0 = srcs[j];
        u32 q0 = ((const u32*)(Xp + (size_t)s0 * C_N))[lane];
        float l0, h0; unpack2(q0, l0, h0);
        a0 += l0; a1 += h0;
    }
    float2 w; w.x = a0; w.y = a1;
    ((float2*)Ysum)[(size_t)e * 64 + lane] = w;
}

// ---------- seg_v: out[v][c] = relu( sum Yp[src][c] / max(len,1) )  (1 wave per vertex) ----------
__global__ __launch_bounds__(256) void seg_v_k(const u16* __restrict__ Yp,
                                               const int* __restrict__ off,
                                               const int* __restrict__ srcs,
                                               float* __restrict__ out, int V) {
    int v = blockIdx.x * 4 + (threadIdx.x >> 6);
    if (v >= V) return;
    int lane = threadIdx.x & 63;
    int j0 = off[v], j1 = off[v + 1];
    float a0 = 0.f, a1 = 0.f;
    int j = j0;
    for (; j + 1 < j1; j += 2) {
        int s0 = srcs[j], s1 = srcs[j + 1];
        u32 q0 = ((const u32*)(Yp + (size_t)s0 * C_N))[lane];
        u32 q1 = ((const u32*)(Yp + (size_t)s1 * C_N))[lane];
        float l0, h0, l1, h1;
        unpack2(q0, l0, h0); unpack2(q1, l1, h1);
        a0 += l0 + l1; a1 += h0 + h1;
    }
    if (j < j1) {
        int s0 = srcs[j];
        u32 q0 = ((const u32*)(Yp + (size_t)s0 * C_N))[lane];
        float l0, h0; unpack2(q0, l0, h0);
        a0 += l0; a1 += h0;
    }
    float inv = 1.0f / (float)max(j1 - j0, 1);
    float2 w;
    w.x = fmaxf(a0 * inv, 0.f);
    w.y = fmaxf(a1 * inv, 0.f);
    ((float2*)out)[(size_t)v * 64 + lane] = w;
}

// ---------- launch ----------
extern "C" void kernel_launch(void* const* d_in, const int* in_sizes, int n_in,
                              void* d_out, int out_size, void* d_ws, size_t ws_size,
                              hipStream_t stream) {
    const float* X     = (const float*)d_in[0];
    const float* W_v2e = (const float*)d_in[1];
    const float* b_v2e = (const float*)d_in[2];
    const float* W_e2v = (const float*)d_in[3];
    const float* b_e2v = (const float*)d_in[4];
    const int*   v_ids = (const int*)d_in[5];
    const int*   e_ids = (const int*)d_in[6];
    float* out = (float*)d_out;   // f32 [V][128]

    bool sizesOK = (n_in == 7) && (out_size == 12800000)
        && in_sizes[0] == 12800000 && in_sizes[1] == 16384 && in_sizes[2] == 128
        && in_sizes[3] == 16384 && in_sizes[4] == 128
        && in_sizes[5] == 1600000 && in_sizes[6] == 1600000;
    if (!sizesOK) { flagf_k<<<1, 64, 0, stream>>>(out, 1.0e6f); return; }
    if (ws_size < 28000000) { flagf_k<<<1, 64, 0, stream>>>(out, 2.0e6f); return; }
    const int nnz = in_sizes[5];

    // d_out doubles as scratch for the first half (both regions dead before seg_v):
    //   d_out[0,        25.6M)  Xp   bf16 [V][128]
    //   d_out[25.6M,    51.2M)  Ysum f32  [E][128]
    u16*   Xp   = (u16*)d_out;
    float* Ysum = (float*)((char*)d_out + 25600000);

    // ws layout (bytes):
    char* ws = (char*)d_ws;
    u16* Yp     = (u16*)(ws + 0);                   // bf16 [E][128]
    int* se_src = (int*)(ws + 12800000);            // int[nnz]
    int* sv_src = (int*)(ws + 19200000);            // int[nnz]
    int* icnt_e = (int*)(ws + 25600000);            // 50000
    int* icnt_v = (int*)(ws + 25800000);            // 100000
    int* off_e  = (int*)(ws + 26200000);            // 50001 (+pad)
    int* off_v  = (int*)(ws + 26400064);            // 100001 (+pad)
    int* cur_e  = (int*)(ws + 26800128);            // 50000
    int* cur_v  = (int*)(ws + 27000128);            // 100000
    int* part   = (int*)(ws + 27400128);            // 147 block partials

    // zero histograms (icnt_e..icnt_v contiguous: 150000 ints)
    zero_i4<<<(150000 / 4 + 255) / 256, 256, 0, stream>>>((int4*)icnt_e, 150000 / 4);
    hist_k<<<(nnz + 255) / 256, 256, 0, stream>>>(v_ids, e_ids, icnt_e, icnt_v, nnz);
    scan_part_k<<<NBLK_T, 256, 0, stream>>>(icnt_e, icnt_v, part);
    scan_carry_k<<<1, 256, 0, stream>>>(part, off_e, off_v);
    scan_add_k<<<NBLK_T, 256, 0, stream>>>(icnt_e, icnt_v, part, off_e, cur_e, off_v, cur_v);
    fill_k<<<(nnz + 255) / 256, 256, 0, stream>>>(v_ids, e_ids, cur_e, cur_v, se_src, sv_src, nnz);

    gemm_tiled_k<0><<<(V_N + 127) / 128, 256, 0, stream>>>(X, W_v2e, b_v2e, nullptr, Xp, V_N);
    seg_e_k<<<(E_N + 3) / 4, 256, 0, stream>>>(Xp, off_e, se_src, Ysum, E_N);
    gemm_tiled_k<1><<<(E_N + 127) / 128, 256, 0, stream>>>(Ysum, W_e2v, b_e2v, off_e, Yp, E_N);
    seg_v_k<<<(V_N + 3) / 4, 256, 0, stream>>>(Yp, off_v, sv_src, out, V_N);

    (void)ws_size;
}

// Round 2
// 663.177 us; speedup vs baseline: 2.1470x; 1.2192x over previous
//
#include <hip/hip_runtime.h>
#include <stdint.h>

#define V_N 100000
#define E_N 50000
#define C_N 128

#define NXCD 8
#define EPART (E_N / NXCD)    // 6250
#define VPART (V_N / NXCD)    // 12500
#define CHUNK_I4 1024         // int4s per chunk = 4096 entries

typedef unsigned short u16;
typedef unsigned int u32;

// ---------- bf16 helpers ----------
__device__ __forceinline__ u16 f2bf(float f) {
    union { float f; u32 i; } c; c.f = f;
    u32 i = c.i;
    i += 0x7fffu + ((i >> 16) & 1u);   // RNE
    return (u16)(i >> 16);
}
__device__ __forceinline__ void unpack2(u32 u, float& lo, float& hi) {
    union { u32 i; float f; } a, b;
    a.i = u << 16; b.i = u & 0xffff0000u;
    lo = a.f; hi = b.f;
}

__global__ __launch_bounds__(64) void flagf_k(float* out, float v) {
    if (threadIdx.x == 0 && blockIdx.x == 0) out[0] = v;
}

__global__ __launch_bounds__(256) void zero_i4(int4* __restrict__ p, int n) {
    int i = blockIdx.x * 256 + threadIdx.x;
    if (i < n) { int4 z = {0, 0, 0, 0}; p[i] = z; }
}

// ---------- XCD-partitioned histogram ----------
// block b: chunk = b>>3 of the nnz stream, dest-range = b&7 (rides the
// round-robin blockIdx->XCD mapping so all atomics/stores for one key range
// come from one XCD; correctness does not depend on the mapping).
__global__ __launch_bounds__(256) void hist_part_k(const int* __restrict__ v_ids,
                                                   const int* __restrict__ e_ids,
                                                   int* __restrict__ icnt_e,
                                                   int* __restrict__ icnt_v, int nnz) {
    const int part  = blockIdx.x & (NXCD - 1);
    const int chunk = blockIdx.x >> 3;
    const int e_lo = part * EPART, e_hi = e_lo + EPART;
    const int v_lo = part * VPART, v_hi = v_lo + VPART;
    const int nnz4 = nnz >> 2;
    #pragma unroll
    for (int u = 0; u < 4; ++u) {
        int i4 = chunk * CHUNK_I4 + u * 256 + threadIdx.x;
        if (i4 < nnz4) {
            int4 e = ((const int4*)e_ids)[i4];
            int4 v = ((const int4*)v_ids)[i4];
            // preserve old semantics: count only when BOTH ids are valid
            #define HP_PAIR(ee, vv) \
                { if (ee >= e_lo && ee < e_hi && (unsigned)vv < (unsigned)V_N) atomicAdd(icnt_e + ee, 1); \
                  if (vv >= v_lo && vv < v_hi && (unsigned)ee < (unsigned)E_N) atomicAdd(icnt_v + vv, 1); }
            HP_PAIR(e.x, v.x); HP_PAIR(e.y, v.y); HP_PAIR(e.z, v.z); HP_PAIR(e.w, v.w);
            #undef HP_PAIR
        }
    }
}

// ---------- hierarchical exclusive scan: 147 blocks of 1024 elems ----------
#define NBLK_E 49
#define NBLK_V 98
#define NBLK_T (NBLK_E + NBLK_V)

__global__ __launch_bounds__(256) void scan_part_k(const int* __restrict__ icnt_e,
                                                   const int* __restrict__ icnt_v,
                                                   int* __restrict__ part) {
    int b = blockIdx.x;
    const int* cnt; int n; int rb;
    if (b < NBLK_E) { cnt = icnt_e; n = E_N; rb = b; }
    else            { cnt = icnt_v; n = V_N; rb = b - NBLK_E; }
    int i = rb * 1024 + threadIdx.x * 4;
    int s = 0;
    if (i + 3 < n) { int4 q = *(const int4*)(cnt + i); s = q.x + q.y + q.z + q.w; }
    else { for (int j = 0; j < 4; ++j) if (i + j < n) s += cnt[i + j]; }
    for (int d = 32; d; d >>= 1) s += __shfl_down(s, d);
    __shared__ int ws[4];
    if ((threadIdx.x & 63) == 0) ws[threadIdx.x >> 6] = s;
    __syncthreads();
    if (threadIdx.x == 0) part[b] = ws[0] + ws[1] + ws[2] + ws[3];
}

__global__ __launch_bounds__(256) void scan_carry_k(int* __restrict__ part,
                                                    int* __restrict__ off_e,
                                                    int* __restrict__ off_v) {
    __shared__ int s[NBLK_T];
    int t = threadIdx.x;
    if (t < NBLK_T) s[t] = part[t];
    __syncthreads();
    if (t == 0) {
        int run = 0;
        for (int j = 0; j < NBLK_E; ++j) { int x = s[j]; s[j] = run; run += x; }
        off_e[E_N] = run;
    } else if (t == 64) {
        int run = 0;
        for (int j = NBLK_E; j < NBLK_T; ++j) { int x = s[j]; s[j] = run; run += x; }
        off_v[V_N] = run;
    }
    __syncthreads();
    if (t < NBLK_T) part[t] = s[t];
}

__global__ __launch_bounds__(256) void scan_add_k(const int* __restrict__ icnt_e,
                                                  const int* __restrict__ icnt_v,
                                                  const int* __restrict__ part,
                                                  int* __restrict__ off_e, int* __restrict__ cur_e,
                                                  int* __restrict__ off_v, int* __restrict__ cur_v) {
    int b = blockIdx.x;
    const int* cnt; int n; int rb; int* off; int* cur;
    if (b < NBLK_E) { cnt = icnt_e; n = E_N; rb = b;           off = off_e; cur = cur_e; }
    else            { cnt = icnt_v; n = V_N; rb = b - NBLK_E;  off = off_v; cur = cur_v; }
    int tid = threadIdx.x, lane = tid & 63, wid = tid >> 6;
    int i = rb * 1024 + tid * 4;
    int x0 = 0, x1 = 0, x2 = 0, x3 = 0;
    if (i + 3 < n) { int4 q = *(const int4*)(cnt + i); x0 = q.x; x1 = q.y; x2 = q.z; x3 = q.w; }
    else {
        if (i     < n) x0 = cnt[i];
        if (i + 1 < n) x1 = cnt[i + 1];
        if (i + 2 < n) x2 = cnt[i + 2];
    }
    int ts = x0 + x1 + x2 + x3;
    int incl = ts;
    for (int d = 1; d < 64; d <<= 1) { int u = __shfl_up(incl, d); if (lane >= d) incl += u; }
    int texcl = incl - ts;
    __shared__ int wsum[4];
    if (lane == 63) wsum[wid] = incl;
    __syncthreads();
    int carry = part[b];
    for (int w2 = 0; w2 < wid; ++w2) carry += wsum[w2];
    int base = carry + texcl;
    int e0 = base, e1 = base + x0, e2 = e1 + x1, e3 = e2 + x2;
    if (i + 3 < n) {
        int4 o = { e0, e1, e2, e3 };
        *(int4*)(off + i) = o;
        *(int4*)(cur + i) = o;
    } else {
        if (i     < n) { off[i]     = e0; cur[i]     = e0; }
        if (i + 1 < n) { off[i + 1] = e1; cur[i + 1] = e1; }
        if (i + 2 < n) { off[i + 2] = e2; cur[i + 2] = e2; }
    }
}

// ---------- XCD-partitioned CSR fill ----------
// Same chunk x range decomposition as hist_part_k. CSR offsets are monotone in
// the key, so all se_src stores for e-range `part` land in one contiguous
// ~1.6MB slice written only by this XCD -> lines collect all their entries in
// this XCD's L2 before eviction (kills the 16x write amplification).
__global__ __launch_bounds__(256) void fill_part_k(const int* __restrict__ v_ids,
                                                   const int* __restrict__ e_ids,
                                                   int* __restrict__ cur_e, int* __restrict__ cur_v,
                                                   int* __restrict__ se_src, int* __restrict__ sv_src,
                                                   int nnz) {
    const int part  = blockIdx.x & (NXCD - 1);
    const int chunk = blockIdx.x >> 3;
    const int e_lo = part * EPART, e_hi = e_lo + EPART;
    const int v_lo = part * VPART, v_hi = v_lo + VPART;
    const int nnz4 = nnz >> 2;
    #pragma unroll
    for (int u = 0; u < 4; ++u) {
        int i4 = chunk * CHUNK_I4 + u * 256 + threadIdx.x;
        if (i4 < nnz4) {
            int4 e = ((const int4*)e_ids)[i4];
            int4 v = ((const int4*)v_ids)[i4];
            #define FP_PAIR(ee, vv) \
                { if (ee >= e_lo && ee < e_hi && (unsigned)vv < (unsigned)V_N) { \
                      int pe = atomicAdd(cur_e + ee, 1); se_src[pe] = vv; } \
                  if (vv >= v_lo && vv < v_hi && (unsigned)ee < (unsigned)E_N) { \
                      int pv = atomicAdd(cur_v + vv, 1); sv_src[pv] = ee; } }
            FP_PAIR(e.x, v.x); FP_PAIR(e.y, v.y); FP_PAIR(e.z, v.z); FP_PAIR(e.w, v.w);
            #undef FP_PAIR
        }
    }
}

// ---------- tiled GEMM: C[m][n] = bf16( post( sum_k pre(A[m][k])*W[k][n] ) + b[n] ) ----------
// MODE 0: pre=id, post=id (gemm1).  MODE 1: pre=relu, post=*1/max(len,1) (gemm2).
template<int MODE>
__global__ __launch_bounds__(256) void gemm_tiled_k(const float* __restrict__ A,
                                                    const float* __restrict__ W,
                                                    const float* __restrict__ bias,
                                                    const int* __restrict__ off,
                                                    u16* __restrict__ Cout, int M) {
    __shared__ float As[128 * 32];   // float4-chunk swizzled
    __shared__ float Wsh[32 * 128];
    const int tid = threadIdx.x;
    const int tx = tid & 15;     // n-group
    const int ty = tid >> 4;     // m-group (0..15)
    const int m0 = blockIdx.x * 128;

    float acc[8][8];
    #pragma unroll
    for (int i = 0; i < 8; ++i)
        #pragma unroll
        for (int j = 0; j < 8; ++j) acc[i][j] = 0.f;

    for (int kk = 0; kk < 128; kk += 32) {
        __syncthreads();
        #pragma unroll
        for (int u = 0; u < 4; ++u) {
            int f = tid + u * 256;
            int r = f >> 3, c4 = f & 7;
            float4 val = { 0.f, 0.f, 0.f, 0.f };
            if (m0 + r < M) {
                val = *(const float4*)(A + (size_t)(m0 + r) * C_N + kk + c4 * 4);
                if (MODE) {
                    val.x = fmaxf(val.x, 0.f); val.y = fmaxf(val.y, 0.f);
                    val.z = fmaxf(val.z, 0.f); val.w = fmaxf(val.w, 0.f);
                }
            }
            int sc4 = c4 ^ ((r >> 3) & 7);
            *(float4*)(As + r * 32 + sc4 * 4) = val;
        }
        #pragma unroll
        for (int u = 0; u < 4; ++u) {
            int f = tid + u * 256;
            int r = f >> 5, c4 = f & 31;
            *(float4*)(Wsh + r * 128 + c4 * 4) = *(const float4*)(W + (size_t)(kk + r) * C_N + c4 * 4);
        }
        __syncthreads();
        #pragma unroll
        for (int k4 = 0; k4 < 32; k4 += 4) {
            float4 a[8];
            #pragma unroll
            for (int i = 0; i < 8; ++i) {
                int row = ty * 8 + i;
                int sc4 = (k4 >> 2) ^ (ty & 7);
                a[i] = *(const float4*)(As + row * 32 + sc4 * 4);
            }
            #pragma unroll
            for (int dk = 0; dk < 4; ++dk) {
                float4 w0 = *(const float4*)(Wsh + (k4 + dk) * 128 + tx * 4);
                float4 w1 = *(const float4*)(Wsh + (k4 + dk) * 128 + 64 + tx * 4);
                #pragma unroll
                for (int i = 0; i < 8; ++i) {
                    float av = (dk == 0) ? a[i].x : (dk == 1) ? a[i].y : (dk == 2) ? a[i].z : a[i].w;
                    acc[i][0] = fmaf(av, w0.x, acc[i][0]);
                    acc[i][1] = fmaf(av, w0.y, acc[i][1]);
                    acc[i][2] = fmaf(av, w0.z, acc[i][2]);
                    acc[i][3] = fmaf(av, w0.w, acc[i][3]);
                    acc[i][4] = fmaf(av, w1.x, acc[i][4]);
                    acc[i][5] = fmaf(av, w1.y, acc[i][5]);
                    acc[i][6] = fmaf(av, w1.z, acc[i][6]);
                    acc[i][7] = fmaf(av, w1.w, acc[i][7]);
                }
            }
        }
    }

    float4 bb0 = *(const float4*)(bias + tx * 4);
    float4 bb1 = *(const float4*)(bias + 64 + tx * 4);
    #pragma unroll
    for (int i = 0; i < 8; ++i) {
        int m = m0 + ty * 8 + i;
        if (m >= M) break;
        float inv = 1.f;
        if (MODE) { int len = off[m + 1] - off[m]; inv = 1.f / (float)max(len, 1); }
        float v0, v1, v2, v3, v4, v5, v6, v7;
        if (MODE) {
            v0 = acc[i][0] * inv + bb0.x; v1 = acc[i][1] * inv + bb0.y;
            v2 = acc[i][2] * inv + bb0.z; v3 = acc[i][3] * inv + bb0.w;
            v4 = acc[i][4] * inv + bb1.x; v5 = acc[i][5] * inv + bb1.y;
            v6 = acc[i][6] * inv + bb1.z; v7 = acc[i][7] * inv + bb1.w;
        } else {
            v0 = acc[i][0] + bb0.x; v1 = acc[i][1] + bb0.y;
            v2 = acc[i][2] + bb0.z; v3 = acc[i][3] + bb0.w;
            v4 = acc[i][4] + bb1.x; v5 = acc[i][5] + bb1.y;
            v6 = acc[i][6] + bb1.z; v7 = acc[i][7] + bb1.w;
        }
        u32 p0 = (u32)f2bf(v0) | ((u32)f2bf(v1) << 16);
        u32 p1 = (u32)f2bf(v2) | ((u32)f2bf(v3) << 16);
        u32 p2 = (u32)f2bf(v4) | ((u32)f2bf(v5) << 16);
        u32 p3 = (u32)f2bf(v6) | ((u32)f2bf(v7) << 16);
        u32* dst = (u32*)(Cout + (size_t)m * C_N);
        uint2 q0 = { p0, p1 }, q1 = { p2, p3 };
        *(uint2*)(dst + tx * 2) = q0;
        *(uint2*)(dst + 32 + tx * 2) = q1;
    }
}

// ---------- seg_e: Ysum[e][c] = sum over segment of Xp[src][c]  (1 wave per edge) ----------
__global__ __launch_bounds__(256) void seg_e_k(const u16* __restrict__ Xp,
                                               const int* __restrict__ off,
                                               const int* __restrict__ srcs,
                                               float* __restrict__ Ysum, int E) {
    int e = blockIdx.x * 4 + (threadIdx.x >> 6);
    if (e >= E) return;
    int lane = threadIdx.x & 63;
    int j0 = off[e], j1 = off[e + 1];
    float a0 = 0.f, a1 = 0.f;
    int j = j0;
    for (; j + 1 < j1; j += 2) {
        int s0 = srcs[j], s1 = srcs[j + 1];
        u32 q0 = ((const u32*)(Xp + (size_t)s0 * C_N))[lane];
        u32 q1 = ((const u32*)(Xp + (size_t)s1 * C_N))[lane];
        float l0, h0, l1, h1;
        unpack2(q0, l0, h0); unpack2(q1, l1, h1);
        a0 += l0 + l1; a1 += h0 + h1;
    }
    if (j < j1) {
        int s0 = srcs[j];
        u32 q0 = ((const u32*)(Xp + (size_t)s0 * C_N))[lane];
        float l0, h0; unpack2(q0, l0, h0);
        a0 += l0; a1 += h0;
    }
    float2 w; w.x = a0; w.y = a1;
    ((float2*)Ysum)[(size_t)e * 64 + lane] = w;
}

// ---------- seg_v: out[v][c] = relu( sum Yp[src][c] / max(len,1) )  (1 wave per vertex) ----------
__global__ __launch_bounds__(256) void seg_v_k(const u16* __restrict__ Yp,
                                               const int* __restrict__ off,
                                               const int* __restrict__ srcs,
                                               float* __restrict__ out, int V) {
    int v = blockIdx.x * 4 + (threadIdx.x >> 6);
    if (v >= V) return;
    int lane = threadIdx.x & 63;
    int j0 = off[v], j1 = off[v + 1];
    float a0 = 0.f, a1 = 0.f;
    int j = j0;
    for (; j + 1 < j1; j += 2) {
        int s0 = srcs[j], s1 = srcs[j + 1];
        u32 q0 = ((const u32*)(Yp + (size_t)s0 * C_N))[lane];
        u32 q1 = ((const u32*)(Yp + (size_t)s1 * C_N))[lane];
        float l0, h0, l1, h1;
        unpack2(q0, l0, h0); unpack2(q1, l1, h1);
        a0 += l0 + l1; a1 += h0 + h1;
    }
    if (j < j1) {
        int s0 = srcs[j];
        u32 q0 = ((const u32*)(Yp + (size_t)s0 * C_N))[lane];
        float l0, h0; unpack2(q0, l0, h0);
        a0 += l0; a1 += h0;
    }
    float inv = 1.0f / (float)max(j1 - j0, 1);
    float2 w;
    w.x = fmaxf(a0 * inv, 0.f);
    w.y = fmaxf(a1 * inv, 0.f);
    ((float2*)out)[(size_t)v * 64 + lane] = w;
}

// ---------- launch ----------
extern "C" void kernel_launch(void* const* d_in, const int* in_sizes, int n_in,
                              void* d_out, int out_size, void* d_ws, size_t ws_size,
                              hipStream_t stream) {
    const float* X     = (const float*)d_in[0];
    const float* W_v2e = (const float*)d_in[1];
    const float* b_v2e = (const float*)d_in[2];
    const float* W_e2v = (const float*)d_in[3];
    const float* b_e2v = (const float*)d_in[4];
    const int*   v_ids = (const int*)d_in[5];
    const int*   e_ids = (const int*)d_in[6];
    float* out = (float*)d_out;   // f32 [V][128]

    bool sizesOK = (n_in == 7) && (out_size == 12800000)
        && in_sizes[0] == 12800000 && in_sizes[1] == 16384 && in_sizes[2] == 128
        && in_sizes[3] == 16384 && in_sizes[4] == 128
        && in_sizes[5] == 1600000 && in_sizes[6] == 1600000;
    if (!sizesOK) { flagf_k<<<1, 64, 0, stream>>>(out, 1.0e6f); return; }
    if (ws_size < 28000000) { flagf_k<<<1, 64, 0, stream>>>(out, 2.0e6f); return; }
    const int nnz = in_sizes[5];

    // d_out doubles as scratch for the first half (both regions dead before seg_v):
    //   d_out[0,        25.6M)  Xp   bf16 [V][128]
    //   d_out[25.6M,    51.2M)  Ysum f32  [E][128]
    u16*   Xp   = (u16*)d_out;
    float* Ysum = (float*)((char*)d_out + 25600000);

    // ws layout (bytes):
    char* ws = (char*)d_ws;
    u16* Yp     = (u16*)(ws + 0);                   // bf16 [E][128]
    int* se_src = (int*)(ws + 12800000);            // int[nnz]
    int* sv_src = (int*)(ws + 19200000);            // int[nnz]
    int* icnt_e = (int*)(ws + 25600000);            // 50000
    int* icnt_v = (int*)(ws + 25800000);            // 100000
    int* off_e  = (int*)(ws + 26200000);            // 50001 (+pad)
    int* off_v  = (int*)(ws + 26400064);            // 100001 (+pad)
    int* cur_e  = (int*)(ws + 26800128);            // 50000
    int* cur_v  = (int*)(ws + 27000128);            // 100000
    int* part   = (int*)(ws + 27400128);            // 147 block partials

    // zero histograms (icnt_e..icnt_v contiguous: 150000 ints)
    zero_i4<<<(150000 / 4 + 255) / 256, 256, 0, stream>>>((int4*)icnt_e, 150000 / 4);

    const int nnz4 = nnz >> 2;
    const int nchunks = (nnz4 + CHUNK_I4 - 1) / CHUNK_I4;   // 391
    hist_part_k<<<nchunks * NXCD, 256, 0, stream>>>(v_ids, e_ids, icnt_e, icnt_v, nnz);
    scan_part_k<<<NBLK_T, 256, 0, stream>>>(icnt_e, icnt_v, part);
    scan_carry_k<<<1, 256, 0, stream>>>(part, off_e, off_v);
    scan_add_k<<<NBLK_T, 256, 0, stream>>>(icnt_e, icnt_v, part, off_e, cur_e, off_v, cur_v);
    fill_part_k<<<nchunks * NXCD, 256, 0, stream>>>(v_ids, e_ids, cur_e, cur_v, se_src, sv_src, nnz);

    gemm_tiled_k<0><<<(V_N + 127) / 128, 256, 0, stream>>>(X, W_v2e, b_v2e, nullptr, Xp, V_N);
    seg_e_k<<<(E_N + 3) / 4, 256, 0, stream>>>(Xp, off_e, se_src, Ysum, E_N);
    gemm_tiled_k<1><<<(E_N + 127) / 128, 256, 0, stream>>>(Ysum, W_e2v, b_e2v, off_e, Yp, E_N);
    seg_v_k<<<(V_N + 3) / 4, 256, 0, stream>>>(Yp, off_v, sv_src, out, V_N);

    (void)ws_size;
}

// Round 3
// 444.504 us; speedup vs baseline: 3.2032x; 1.4919x over previous
//
#include <hip/hip_runtime.h>
#include <stdint.h>

#define V_N 100000
#define E_N 50000
#define C_N 128

// counting-sort geometry: 256 keys per bucket
#define NB_E 196                 // ceil(50000/256)
#define NB_V 391                 // ceil(100000/256)
#define NBINS (NB_E + NB_V)      // 587
#define CHUNK 8192               // entries per pass-A/hist block
#define CAP_B 10240              // passB LDS value-staging capacity (mean 8192/4096, +20 sigma)

typedef unsigned short u16;
typedef unsigned int u32;

// ---------- bf16 helpers ----------
__device__ __forceinline__ u16 f2bf(float f) {
    union { float f; u32 i; } c; c.f = f;
    u32 i = c.i;
    i += 0x7fffu + ((i >> 16) & 1u);   // RNE
    return (u16)(i >> 16);
}
__device__ __forceinline__ void unpack2(u32 u, float& lo, float& hi) {
    union { u32 i; float f; } a, b;
    a.i = u << 16; b.i = u & 0xffff0000u;
    lo = a.f; hi = b.f;
}

__global__ __launch_bounds__(64) void flagf_k(float* out, float v) {
    if (threadIdx.x == 0 && blockIdx.x == 0) out[0] = v;
}

__global__ __launch_bounds__(256) void zero_i4(int4* __restrict__ p, int n) {
    int i = blockIdx.x * 256 + threadIdx.x;
    if (i < n) { int4 z = {0, 0, 0, 0}; p[i] = z; }
}

// ---------- histA: global bucket totals (LDS-privatized, ~100K bucket atomics) ----------
__global__ __launch_bounds__(256) void histA_k(const int* __restrict__ v_ids,
                                               const int* __restrict__ e_ids,
                                               int* __restrict__ gbin, int nnz) {
    __shared__ int hb[NBINS];
    for (int i = threadIdx.x; i < NBINS; i += 256) hb[i] = 0;
    __syncthreads();
    const int nnz4 = nnz >> 2;
    const int b4 = blockIdx.x * (CHUNK >> 2);
    #pragma unroll
    for (int u = 0; u < 8; ++u) {
        int i4 = b4 + u * 256 + threadIdx.x;
        if (i4 < nnz4) {
            int4 e = ((const int4*)e_ids)[i4];
            int4 v = ((const int4*)v_ids)[i4];
            #define HA(ee, vv) \
                if ((unsigned)ee < (unsigned)E_N && (unsigned)vv < (unsigned)V_N) { \
                    atomicAdd(&hb[ee >> 8], 1); atomicAdd(&hb[NB_E + (vv >> 8)], 1); }
            HA(e.x, v.x); HA(e.y, v.y); HA(e.z, v.z); HA(e.w, v.w);
            #undef HA
        }
    }
    __syncthreads();
    for (int i = threadIdx.x; i < NBINS; i += 256)
        if (hb[i]) atomicAdd(&gbin[i], hb[i]);
}

// ---------- scanB: exclusive scan over bucket totals -> bases + cursors + off[N] ----------
__global__ __launch_bounds__(1024) void scanB_k(const int* __restrict__ gbin,
                                                int* __restrict__ base_e, int* __restrict__ base_v,
                                                int* __restrict__ curb_e, int* __restrict__ curb_v,
                                                int* __restrict__ off_e, int* __restrict__ off_v) {
    __shared__ int wtot[16];
    const int t = threadIdx.x, lane = t & 63, wid = t >> 6;
    // ---- e buckets ----
    {
        int x = (t < NB_E) ? gbin[t] : 0;
        int incl = x;
        for (int d = 1; d < 64; d <<= 1) { int u = __shfl_up(incl, d); if (lane >= d) incl += u; }
        if (lane == 63) wtot[wid] = incl;
        __syncthreads();
        int carry = 0;
        for (int w = 0; w < wid; ++w) carry += wtot[w];
        int excl = carry + incl - x;
        if (t < NB_E) { base_e[t] = excl; curb_e[t] = excl; }
        if (t == 0) {
            int tot = 0;
            for (int w = 0; w < 16; ++w) tot += wtot[w];
            base_e[NB_E] = tot; off_e[E_N] = tot;
        }
        __syncthreads();
    }
    // ---- v buckets ----
    {
        int x = (t < NB_V) ? gbin[NB_E + t] : 0;
        int incl = x;
        for (int d = 1; d < 64; d <<= 1) { int u = __shfl_up(incl, d); if (lane >= d) incl += u; }
        if (lane == 63) wtot[wid] = incl;
        __syncthreads();
        int carry = 0;
        for (int w = 0; w < wid; ++w) carry += wtot[w];
        int excl = carry + incl - x;
        if (t < NB_V) { base_v[t] = excl; curb_v[t] = excl; }
        if (t == 0) {
            int tot = 0;
            for (int w = 0; w < 16; ++w) tot += wtot[w];
            base_v[NB_V] = tot; off_v[V_N] = tot;
        }
    }
}

// ---------- passA: partition pairs into bucket-contiguous arrays, coalesced writes ----------
// pair pack: e-dir (elow 8b << 17) | v (17b);  v-dir (vlow 8b << 16) | e (16b)
__global__ __launch_bounds__(512) void passA_k(const int* __restrict__ v_ids,
                                               const int* __restrict__ e_ids,
                                               int* __restrict__ curb_e, int* __restrict__ curb_v,
                                               u32* __restrict__ pairs_e, u32* __restrict__ pairs_v,
                                               int nnz) {
    __shared__ u32 stage[CHUNK];
    __shared__ int cnt[512], runoff[513], delta[512], cnt2[512];
    __shared__ int wtot[8];
    const int t = threadIdx.x, lane = t & 63, wid = t >> 6;
    const int nnz4 = nnz >> 2;
    const int b4 = blockIdx.x * (CHUNK >> 2);

    for (int dir = 0; dir < 2; ++dir) {
        const int nb = dir ? NB_V : NB_E;
        for (int i = t; i < nb; i += 512) { cnt[i] = 0; cnt2[i] = 0; }
        __syncthreads();
        // count
        #pragma unroll
        for (int u = 0; u < 4; ++u) {
            int i4 = b4 + u * 512 + t;
            if (i4 < nnz4) {
                int4 e = ((const int4*)e_ids)[i4];
                int4 v = ((const int4*)v_ids)[i4];
                #define PC(ee, vv) \
                    if ((unsigned)ee < (unsigned)E_N && (unsigned)vv < (unsigned)V_N) { \
                        int k_ = dir ? vv : ee; atomicAdd(&cnt[k_ >> 8], 1); }
                PC(e.x, v.x); PC(e.y, v.y); PC(e.z, v.z); PC(e.w, v.w);
                #undef PC
            }
        }
        __syncthreads();
        // exclusive scan cnt[0..nb)
        int x = (t < nb) ? cnt[t] : 0;
        int incl = x;
        for (int d = 1; d < 64; d <<= 1) { int u = __shfl_up(incl, d); if (lane >= d) incl += u; }
        if (lane == 63) wtot[wid] = incl;
        __syncthreads();
        int carry = 0;
        for (int w = 0; w < wid; ++w) carry += wtot[w];
        int excl = carry + incl - x;
        if (t < nb) runoff[t] = excl;
        if (t == 0) {
            int tot = 0;
            for (int w = 0; w < 8; ++w) tot += wtot[w];
            runoff[nb] = tot;
        }
        __syncthreads();
        const int total = runoff[nb];
        // reserve global runs (one atomic per nonempty bucket)
        if (t < nb && cnt[t] > 0) {
            int r = atomicAdd((dir ? curb_v : curb_e) + t, cnt[t]);
            delta[t] = r - runoff[t];
        }
        __syncthreads();
        // scatter into LDS staging grouped by bucket
        #pragma unroll
        for (int u = 0; u < 4; ++u) {
            int i4 = b4 + u * 512 + t;
            if (i4 < nnz4) {
                int4 e = ((const int4*)e_ids)[i4];
                int4 v = ((const int4*)v_ids)[i4];
                #define PS(ee, vv) \
                    if ((unsigned)ee < (unsigned)E_N && (unsigned)vv < (unsigned)V_N) { \
                        int k_ = dir ? vv : ee; int b_ = k_ >> 8; \
                        u32 pk_ = dir ? (((u32)(k_ & 255) << 16) | (u32)ee) \
                                      : (((u32)(k_ & 255) << 17) | (u32)vv); \
                        int idx_ = runoff[b_] + atomicAdd(&cnt2[b_], 1); \
                        stage[idx_] = pk_; }
                PS(e.x, v.x); PS(e.y, v.y); PS(e.z, v.z); PS(e.w, v.w);
                #undef PS
            }
        }
        __syncthreads();
        // coalesced flush (binary-search bucket of each staged slot)
        u32* pairs = dir ? pairs_v : pairs_e;
        for (int i = t; i < total; i += 512) {
            int lo = 0, hi = nb;
            while (hi - lo > 1) { int mid = (lo + hi) >> 1; if (runoff[mid] <= i) lo = mid; else hi = mid; }
            pairs[i + delta[lo]] = stage[i];
        }
        __syncthreads();
    }
}

// ---------- passB: per-bucket CSR finalize, LDS-staged, coalesced in/out ----------
__global__ __launch_bounds__(256) void passB_k(const u32* __restrict__ pairs_e,
                                               const u32* __restrict__ pairs_v,
                                               const int* __restrict__ base_e,
                                               const int* __restrict__ base_v,
                                               int* __restrict__ off_e, int* __restrict__ off_v,
                                               int* __restrict__ se_src, int* __restrict__ sv_src) {
    __shared__ int cntk[256], curk[256];
    __shared__ u32 buf[CAP_B];
    __shared__ int wtot[4];
    int b = blockIdx.x;
    const u32* pairs; const int* base; int* off; int* outv; int keyN, shift; u32 mask;
    if (b < NB_E) { pairs = pairs_e; base = base_e; off = off_e; outv = se_src; keyN = E_N; shift = 17; mask = 0x1FFFFu; }
    else { b -= NB_E; pairs = pairs_v; base = base_v; off = off_v; outv = sv_src; keyN = V_N; shift = 16; mask = 0xFFFFu; }
    const int lo = base[b], hi = base[b + 1], cnt = hi - lo, k0 = b << 8;
    const int t = threadIdx.x, lane = t & 63, wid = t >> 6;
    cntk[t] = 0;
    __syncthreads();
    for (int i = t; i < cnt; i += 256) { u32 p = pairs[lo + i]; atomicAdd(&cntk[p >> shift], 1); }
    __syncthreads();
    int x = cntk[t];
    int incl = x;
    for (int d = 1; d < 64; d <<= 1) { int u = __shfl_up(incl, d); if (lane >= d) incl += u; }
    if (lane == 63) wtot[wid] = incl;
    __syncthreads();
    int carry = 0;
    for (int w = 0; w < wid; ++w) carry += wtot[w];
    int excl = carry + incl - x;
    if (k0 + t < keyN) off[k0 + t] = lo + excl;
    curk[t] = excl;
    __syncthreads();
    if (cnt <= CAP_B) {
        for (int i = t; i < cnt; i += 256) {
            u32 p = pairs[lo + i];
            int pos = atomicAdd(&curk[p >> shift], 1);
            buf[pos] = p & mask;
        }
        __syncthreads();
        for (int i = t; i < cnt; i += 256) outv[lo + i] = (int)buf[i];
    } else {
        // statistically unreachable fallback (keeps correctness unconditional)
        for (int i = t; i < cnt; i += 256) {
            u32 p = pairs[lo + i];
            int pos = atomicAdd(&curk[p >> shift], 1);
            outv[lo + pos] = (int)(p & mask);
        }
    }
}

// ---------- tiled GEMM: C[m][n] = bf16( post( sum_k pre(A[m][k])*W[k][n] ) + b[n] ) ----------
// MODE 0: pre=id, post=id (gemm1).  MODE 1: pre=relu, post=*1/max(len,1) (gemm2).
template<int MODE>
__global__ __launch_bounds__(256) void gemm_tiled_k(const float* __restrict__ A,
                                                    const float* __restrict__ W,
                                                    const float* __restrict__ bias,
                                                    const int* __restrict__ off,
                                                    u16* __restrict__ Cout, int M) {
    __shared__ float As[128 * 32];   // float4-chunk swizzled
    __shared__ float Wsh[32 * 128];
    const int tid = threadIdx.x;
    const int tx = tid & 15;     // n-group
    const int ty = tid >> 4;     // m-group (0..15)
    const int m0 = blockIdx.x * 128;

    float acc[8][8];
    #pragma unroll
    for (int i = 0; i < 8; ++i)
        #pragma unroll
        for (int j = 0; j < 8; ++j) acc[i][j] = 0.f;

    for (int kk = 0; kk < 128; kk += 32) {
        __syncthreads();
        #pragma unroll
        for (int u = 0; u < 4; ++u) {
            int f = tid + u * 256;
            int r = f >> 3, c4 = f & 7;
            float4 val = { 0.f, 0.f, 0.f, 0.f };
            if (m0 + r < M) {
                val = *(const float4*)(A + (size_t)(m0 + r) * C_N + kk + c4 * 4);
                if (MODE) {
                    val.x = fmaxf(val.x, 0.f); val.y = fmaxf(val.y, 0.f);
                    val.z = fmaxf(val.z, 0.f); val.w = fmaxf(val.w, 0.f);
                }
            }
            int sc4 = c4 ^ ((r >> 3) & 7);
            *(float4*)(As + r * 32 + sc4 * 4) = val;
        }
        #pragma unroll
        for (int u = 0; u < 4; ++u) {
            int f = tid + u * 256;
            int r = f >> 5, c4 = f & 31;
            *(float4*)(Wsh + r * 128 + c4 * 4) = *(const float4*)(W + (size_t)(kk + r) * C_N + c4 * 4);
        }
        __syncthreads();
        #pragma unroll
        for (int k4 = 0; k4 < 32; k4 += 4) {
            float4 a[8];
            #pragma unroll
            for (int i = 0; i < 8; ++i) {
                int row = ty * 8 + i;
                int sc4 = (k4 >> 2) ^ (ty & 7);
                a[i] = *(const float4*)(As + row * 32 + sc4 * 4);
            }
            #pragma unroll
            for (int dk = 0; dk < 4; ++dk) {
                float4 w0 = *(const float4*)(Wsh + (k4 + dk) * 128 + tx * 4);
                float4 w1 = *(const float4*)(Wsh + (k4 + dk) * 128 + 64 + tx * 4);
                #pragma unroll
                for (int i = 0; i < 8; ++i) {
                    float av = (dk == 0) ? a[i].x : (dk == 1) ? a[i].y : (dk == 2) ? a[i].z : a[i].w;
                    acc[i][0] = fmaf(av, w0.x, acc[i][0]);
                    acc[i][1] = fmaf(av, w0.y, acc[i][1]);
                    acc[i][2] = fmaf(av, w0.z, acc[i][2]);
                    acc[i][3] = fmaf(av, w0.w, acc[i][3]);
                    acc[i][4] = fmaf(av, w1.x, acc[i][4]);
                    acc[i][5] = fmaf(av, w1.y, acc[i][5]);
                    acc[i][6] = fmaf(av, w1.z, acc[i][6]);
                    acc[i][7] = fmaf(av, w1.w, acc[i][7]);
                }
            }
        }
    }

    float4 bb0 = *(const float4*)(bias + tx * 4);
    float4 bb1 = *(const float4*)(bias + 64 + tx * 4);
    #pragma unroll
    for (int i = 0; i < 8; ++i) {
        int m = m0 + ty * 8 + i;
        if (m >= M) break;
        float inv = 1.f;
        if (MODE) { int len = off[m + 1] - off[m]; inv = 1.f / (float)max(len, 1); }
        float v0, v1, v2, v3, v4, v5, v6, v7;
        if (MODE) {
            v0 = acc[i][0] * inv + bb0.x; v1 = acc[i][1] * inv + bb0.y;
            v2 = acc[i][2] * inv + bb0.z; v3 = acc[i][3] * inv + bb0.w;
            v4 = acc[i][4] * inv + bb1.x; v5 = acc[i][5] * inv + bb1.y;
            v6 = acc[i][6] * inv + bb1.z; v7 = acc[i][7] * inv + bb1.w;
        } else {
            v0 = acc[i][0] + bb0.x; v1 = acc[i][1] + bb0.y;
            v2 = acc[i][2] + bb0.z; v3 = acc[i][3] + bb0.w;
            v4 = acc[i][4] + bb1.x; v5 = acc[i][5] + bb1.y;
            v6 = acc[i][6] + bb1.z; v7 = acc[i][7] + bb1.w;
        }
        u32 p0 = (u32)f2bf(v0) | ((u32)f2bf(v1) << 16);
        u32 p1 = (u32)f2bf(v2) | ((u32)f2bf(v3) << 16);
        u32 p2 = (u32)f2bf(v4) | ((u32)f2bf(v5) << 16);
        u32 p3 = (u32)f2bf(v6) | ((u32)f2bf(v7) << 16);
        u32* dst = (u32*)(Cout + (size_t)m * C_N);
        uint2 q0 = { p0, p1 }, q1 = { p2, p3 };
        *(uint2*)(dst + tx * 2) = q0;
        *(uint2*)(dst + 32 + tx * 2) = q1;
    }
}

// ---------- seg_e: Ysum[e][c] = sum over segment of Xp[src][c]  (1 wave per edge) ----------
__global__ __launch_bounds__(256) void seg_e_k(const u16* __restrict__ Xp,
                                               const int* __restrict__ off,
                                               const int* __restrict__ srcs,
                                               float* __restrict__ Ysum, int E) {
    int e = blockIdx.x * 4 + (threadIdx.x >> 6);
    if (e >= E) return;
    int lane = threadIdx.x & 63;
    int j0 = off[e], j1 = off[e + 1];
    float a0 = 0.f, a1 = 0.f;
    int j = j0;
    for (; j + 1 < j1; j += 2) {
        int s0 = srcs[j], s1 = srcs[j + 1];
        u32 q0 = ((const u32*)(Xp + (size_t)s0 * C_N))[lane];
        u32 q1 = ((const u32*)(Xp + (size_t)s1 * C_N))[lane];
        float l0, h0, l1, h1;
        unpack2(q0, l0, h0); unpack2(q1, l1, h1);
        a0 += l0 + l1; a1 += h0 + h1;
    }
    if (j < j1) {
        int s0 = srcs[j];
        u32 q0 = ((const u32*)(Xp + (size_t)s0 * C_N))[lane];
        float l0, h0; unpack2(q0, l0, h0);
        a0 += l0; a1 += h0;
    }
    float2 w; w.x = a0; w.y = a1;
    ((float2*)Ysum)[(size_t)e * 64 + lane] = w;
}

// ---------- seg_v: out[v][c] = relu( sum Yp[src][c] / max(len,1) )  (1 wave per vertex) ----------
__global__ __launch_bounds__(256) void seg_v_k(const u16* __restrict__ Yp,
                                               const int* __restrict__ off,
                                               const int* __restrict__ srcs,
                                               float* __restrict__ out, int V) {
    int v = blockIdx.x * 4 + (threadIdx.x >> 6);
    if (v >= V) return;
    int lane = threadIdx.x & 63;
    int j0 = off[v], j1 = off[v + 1];
    float a0 = 0.f, a1 = 0.f;
    int j = j0;
    for (; j + 1 < j1; j += 2) {
        int s0 = srcs[j], s1 = srcs[j + 1];
        u32 q0 = ((const u32*)(Yp + (size_t)s0 * C_N))[lane];
        u32 q1 = ((const u32*)(Yp + (size_t)s1 * C_N))[lane];
        float l0, h0, l1, h1;
        unpack2(q0, l0, h0); unpack2(q1, l1, h1);
        a0 += l0 + l1; a1 += h0 + h1;
    }
    if (j < j1) {
        int s0 = srcs[j];
        u32 q0 = ((const u32*)(Yp + (size_t)s0 * C_N))[lane];
        float l0, h0; unpack2(q0, l0, h0);
        a0 += l0; a1 += h0;
    }
    float inv = 1.0f / (float)max(j1 - j0, 1);
    float2 w;
    w.x = fmaxf(a0 * inv, 0.f);
    w.y = fmaxf(a1 * inv, 0.f);
    ((float2*)out)[(size_t)v * 64 + lane] = w;
}

// ---------- launch ----------
extern "C" void kernel_launch(void* const* d_in, const int* in_sizes, int n_in,
                              void* d_out, int out_size, void* d_ws, size_t ws_size,
                              hipStream_t stream) {
    const float* X     = (const float*)d_in[0];
    const float* W_v2e = (const float*)d_in[1];
    const float* b_v2e = (const float*)d_in[2];
    const float* W_e2v = (const float*)d_in[3];
    const float* b_e2v = (const float*)d_in[4];
    const int*   v_ids = (const int*)d_in[5];
    const int*   e_ids = (const int*)d_in[6];
    float* out = (float*)d_out;   // f32 [V][128]

    bool sizesOK = (n_in == 7) && (out_size == 12800000)
        && in_sizes[0] == 12800000 && in_sizes[1] == 16384 && in_sizes[2] == 128
        && in_sizes[3] == 16384 && in_sizes[4] == 128
        && in_sizes[5] == 1600000 && in_sizes[6] == 1600000;
    if (!sizesOK) { flagf_k<<<1, 64, 0, stream>>>(out, 1.0e6f); return; }
    if (ws_size < 28000000) { flagf_k<<<1, 64, 0, stream>>>(out, 2.0e6f); return; }
    const int nnz = in_sizes[5];

    // d_out doubles as scratch:
    //   phase 1 (sort):  pairs_e u32[nnz] @0 (6.4M), pairs_v u32[nnz] @6.4M  (dead after passB)
    //   phase 2 (gemm):  Xp bf16 [V][128] @0 (25.6M), Ysum f32 [E][128] @25.6M
    u32*   pairs_e = (u32*)d_out;
    u32*   pairs_v = pairs_e + nnz;
    u16*   Xp   = (u16*)d_out;
    float* Ysum = (float*)((char*)d_out + 25600000);

    // ws layout (bytes):
    char* ws = (char*)d_ws;
    u16* Yp     = (u16*)(ws + 0);                   // bf16 [E][128] (12.8M)
    int* se_src = (int*)(ws + 12800000);            // int[nnz]
    int* sv_src = (int*)(ws + 19200000);            // int[nnz]
    int* gbin   = (int*)(ws + 25600000);            // 587 (+pad to 640)
    int* base_e = (int*)(ws + 25602560);            // 197
    int* base_v = (int*)(ws + 25603584);            // 392
    int* curb_e = (int*)(ws + 25605632);            // 196
    int* curb_v = (int*)(ws + 25606656);            // 391
    int* off_e  = (int*)(ws + 25608704);            // 50001
    int* off_v  = (int*)(ws + 25808768);            // 100001  (ends ~26.2M)

    const int NCH = (nnz + CHUNK - 1) / CHUNK;      // 196

    zero_i4<<<1, 256, 0, stream>>>((int4*)gbin, 152);   // 608 ints >= 587, within pad
    histA_k<<<NCH, 256, 0, stream>>>(v_ids, e_ids, gbin, nnz);
    scanB_k<<<1, 1024, 0, stream>>>(gbin, base_e, base_v, curb_e, curb_v, off_e, off_v);
    passA_k<<<NCH, 512, 0, stream>>>(v_ids, e_ids, curb_e, curb_v, pairs_e, pairs_v, nnz);
    passB_k<<<NBINS, 256, 0, stream>>>(pairs_e, pairs_v, base_e, base_v, off_e, off_v, se_src, sv_src);

    gemm_tiled_k<0><<<(V_N + 127) / 128, 256, 0, stream>>>(X, W_v2e, b_v2e, nullptr, Xp, V_N);
    seg_e_k<<<(E_N + 3) / 4, 256, 0, stream>>>(Xp, off_e, se_src, Ysum, E_N);
    gemm_tiled_k<1><<<(E_N + 127) / 128, 256, 0, stream>>>(Ysum, W_e2v, b_e2v, off_e, Yp, E_N);
    seg_v_k<<<(V_N + 3) / 4, 256, 0, stream>>>(Yp, off_v, sv_src, out, V_N);

    (void)ws_size;
}

// Round 4
// 371.061 us; speedup vs baseline: 3.8373x; 1.1979x over previous
//
#include <hip/hip_runtime.h>
#include <stdint.h>

#define V_N 100000
#define E_N 50000
#define C_N 128

// counting-sort geometry: 256 keys per bucket
#define NB_E 196                 // ceil(50000/256)
#define NB_V 391                 // ceil(100000/256)
#define NBINS (NB_E + NB_V)      // 587
#define CHUNK 8192               // entries per pass-A/hist block
#define CAP_B 10240              // passB LDS value-staging capacity (mean 8192/4096, +20 sigma)
#define G1B 782                  // gemm1 blocks = ceil(V_N/128)

typedef unsigned short u16;
typedef unsigned int u32;

// ---------- bf16 helpers ----------
__device__ __forceinline__ u16 f2bf(float f) {
    union { float f; u32 i; } c; c.f = f;
    u32 i = c.i;
    i += 0x7fffu + ((i >> 16) & 1u);   // RNE
    return (u16)(i >> 16);
}
__device__ __forceinline__ void unpack2(u32 u, float& lo, float& hi) {
    union { u32 i; float f; } a, b;
    a.i = u << 16; b.i = u & 0xffff0000u;
    lo = a.f; hi = b.f;
}

__global__ __launch_bounds__(64) void flagf_k(float* out, float v) {
    if (threadIdx.x == 0 && blockIdx.x == 0) out[0] = v;
}

__global__ __launch_bounds__(256) void zero_i4(int4* __restrict__ p, int n) {
    int i = blockIdx.x * 256 + threadIdx.x;
    if (i < n) { int4 z = {0, 0, 0, 0}; p[i] = z; }
}

// ---------- tiled GEMM body: C[m][n] = bf16( post( sum_k pre(A[m][k])*W[k][n] ) + b[n] ) ----------
// MODE 0: pre=id, post=id.  MODE 1: pre=relu, post=*1/max(len,1).
template<int MODE>
__device__ __forceinline__ void gemm_body(float* As, float* Wsh, int bid,
                                          const float* __restrict__ A,
                                          const float* __restrict__ W,
                                          const float* __restrict__ bias,
                                          const int* __restrict__ off,
                                          u16* __restrict__ Cout, int M) {
    const int tid = threadIdx.x;
    const int tx = tid & 15;     // n-group
    const int ty = tid >> 4;     // m-group (0..15)
    const int m0 = bid * 128;

    float acc[8][8];
    #pragma unroll
    for (int i = 0; i < 8; ++i)
        #pragma unroll
        for (int j = 0; j < 8; ++j) acc[i][j] = 0.f;

    for (int kk = 0; kk < 128; kk += 32) {
        __syncthreads();
        #pragma unroll
        for (int u = 0; u < 4; ++u) {
            int f = tid + u * 256;
            int r = f >> 3, c4 = f & 7;
            float4 val = { 0.f, 0.f, 0.f, 0.f };
            if (m0 + r < M) {
                val = *(const float4*)(A + (size_t)(m0 + r) * C_N + kk + c4 * 4);
                if (MODE) {
                    val.x = fmaxf(val.x, 0.f); val.y = fmaxf(val.y, 0.f);
                    val.z = fmaxf(val.z, 0.f); val.w = fmaxf(val.w, 0.f);
                }
            }
            int sc4 = c4 ^ ((r >> 3) & 7);
            *(float4*)(As + r * 32 + sc4 * 4) = val;
        }
        #pragma unroll
        for (int u = 0; u < 4; ++u) {
            int f = tid + u * 256;
            int r = f >> 5, c4 = f & 31;
            *(float4*)(Wsh + r * 128 + c4 * 4) = *(const float4*)(W + (size_t)(kk + r) * C_N + c4 * 4);
        }
        __syncthreads();
        #pragma unroll
        for (int k4 = 0; k4 < 32; k4 += 4) {
            float4 a[8];
            #pragma unroll
            for (int i = 0; i < 8; ++i) {
                int row = ty * 8 + i;
                int sc4 = (k4 >> 2) ^ (ty & 7);
                a[i] = *(const float4*)(As + row * 32 + sc4 * 4);
            }
            #pragma unroll
            for (int dk = 0; dk < 4; ++dk) {
                float4 w0 = *(const float4*)(Wsh + (k4 + dk) * 128 + tx * 4);
                float4 w1 = *(const float4*)(Wsh + (k4 + dk) * 128 + 64 + tx * 4);
                #pragma unroll
                for (int i = 0; i < 8; ++i) {
                    float av = (dk == 0) ? a[i].x : (dk == 1) ? a[i].y : (dk == 2) ? a[i].z : a[i].w;
                    acc[i][0] = fmaf(av, w0.x, acc[i][0]);
                    acc[i][1] = fmaf(av, w0.y, acc[i][1]);
                    acc[i][2] = fmaf(av, w0.z, acc[i][2]);
                    acc[i][3] = fmaf(av, w0.w, acc[i][3]);
                    acc[i][4] = fmaf(av, w1.x, acc[i][4]);
                    acc[i][5] = fmaf(av, w1.y, acc[i][5]);
                    acc[i][6] = fmaf(av, w1.z, acc[i][6]);
                    acc[i][7] = fmaf(av, w1.w, acc[i][7]);
                }
            }
        }
    }

    float4 bb0 = *(const float4*)(bias + tx * 4);
    float4 bb1 = *(const float4*)(bias + 64 + tx * 4);
    #pragma unroll
    for (int i = 0; i < 8; ++i) {
        int m = m0 + ty * 8 + i;
        if (m >= M) break;
        float inv = 1.f;
        if (MODE) { int len = off[m + 1] - off[m]; inv = 1.f / (float)max(len, 1); }
        float v0, v1, v2, v3, v4, v5, v6, v7;
        if (MODE) {
            v0 = acc[i][0] * inv + bb0.x; v1 = acc[i][1] * inv + bb0.y;
            v2 = acc[i][2] * inv + bb0.z; v3 = acc[i][3] * inv + bb0.w;
            v4 = acc[i][4] * inv + bb1.x; v5 = acc[i][5] * inv + bb1.y;
            v6 = acc[i][6] * inv + bb1.z; v7 = acc[i][7] * inv + bb1.w;
        } else {
            v0 = acc[i][0] + bb0.x; v1 = acc[i][1] + bb0.y;
            v2 = acc[i][2] + bb0.z; v3 = acc[i][3] + bb0.w;
            v4 = acc[i][4] + bb1.x; v5 = acc[i][5] + bb1.y;
            v6 = acc[i][6] + bb1.z; v7 = acc[i][7] + bb1.w;
        }
        u32 p0 = (u32)f2bf(v0) | ((u32)f2bf(v1) << 16);
        u32 p1 = (u32)f2bf(v2) | ((u32)f2bf(v3) << 16);
        u32 p2 = (u32)f2bf(v4) | ((u32)f2bf(v5) << 16);
        u32 p3 = (u32)f2bf(v6) | ((u32)f2bf(v7) << 16);
        u32* dst = (u32*)(Cout + (size_t)m * C_N);
        uint2 q0 = { p0, p1 }, q1 = { p2, p3 };
        *(uint2*)(dst + tx * 2) = q0;
        *(uint2*)(dst + 32 + tx * 2) = q1;
    }
}

template<int MODE>
__global__ __launch_bounds__(256) void gemm_tiled_k(const float* __restrict__ A,
                                                    const float* __restrict__ W,
                                                    const float* __restrict__ bias,
                                                    const int* __restrict__ off,
                                                    u16* __restrict__ Cout, int M) {
    __shared__ __align__(16) float As[128 * 32];
    __shared__ __align__(16) float Wsh[32 * 128];
    gemm_body<MODE>(As, Wsh, blockIdx.x, A, W, bias, off, Cout, M);
}

// ---------- fusedA: blocks [0,G1B) run gemm1; blocks [G1B, G1B+NCH) run histA ----------
__global__ __launch_bounds__(256) void fusedA_k(const float* __restrict__ X,
                                                const float* __restrict__ W,
                                                const float* __restrict__ bias,
                                                u16* __restrict__ Xp,
                                                const int* __restrict__ v_ids,
                                                const int* __restrict__ e_ids,
                                                int* __restrict__ gbin, int nnz) {
    __shared__ __align__(16) char smem[32768];
    if ((int)blockIdx.x < G1B) {
        gemm_body<0>((float*)smem, (float*)(smem + 16384), blockIdx.x,
                     X, W, bias, nullptr, Xp, V_N);
    } else {
        int* hb = (int*)smem;
        const int bid = blockIdx.x - G1B;
        for (int i = threadIdx.x; i < NBINS; i += 256) hb[i] = 0;
        __syncthreads();
        const int nnz4 = nnz >> 2;
        const int b4 = bid * (CHUNK >> 2);
        #pragma unroll
        for (int u = 0; u < 8; ++u) {
            int i4 = b4 + u * 256 + threadIdx.x;
            if (i4 < nnz4) {
                int4 e = ((const int4*)e_ids)[i4];
                int4 v = ((const int4*)v_ids)[i4];
                #define HA(ee, vv) \
                    if ((unsigned)ee < (unsigned)E_N && (unsigned)vv < (unsigned)V_N) { \
                        atomicAdd(&hb[ee >> 8], 1); atomicAdd(&hb[NB_E + (vv >> 8)], 1); }
                HA(e.x, v.x); HA(e.y, v.y); HA(e.z, v.z); HA(e.w, v.w);
                #undef HA
            }
        }
        __syncthreads();
        for (int i = threadIdx.x; i < NBINS; i += 256)
            if (hb[i]) atomicAdd(&gbin[i], hb[i]);
    }
}

// ---------- scanB: exclusive scan over bucket totals -> bases + cursors + off[N] ----------
__global__ __launch_bounds__(1024) void scanB_k(const int* __restrict__ gbin,
                                                int* __restrict__ base_e, int* __restrict__ base_v,
                                                int* __restrict__ curb_e, int* __restrict__ curb_v,
                                                int* __restrict__ off_e, int* __restrict__ off_v) {
    __shared__ int wtot[16];
    const int t = threadIdx.x, lane = t & 63, wid = t >> 6;
    // ---- e buckets ----
    {
        int x = (t < NB_E) ? gbin[t] : 0;
        int incl = x;
        for (int d = 1; d < 64; d <<= 1) { int u = __shfl_up(incl, d); if (lane >= d) incl += u; }
        if (lane == 63) wtot[wid] = incl;
        __syncthreads();
        int carry = 0;
        for (int w = 0; w < wid; ++w) carry += wtot[w];
        int excl = carry + incl - x;
        if (t < NB_E) { base_e[t] = excl; curb_e[t] = excl; }
        if (t == 0) {
            int tot = 0;
            for (int w = 0; w < 16; ++w) tot += wtot[w];
            base_e[NB_E] = tot; off_e[E_N] = tot;
        }
        __syncthreads();
    }
    // ---- v buckets ----
    {
        int x = (t < NB_V) ? gbin[NB_E + t] : 0;
        int incl = x;
        for (int d = 1; d < 64; d <<= 1) { int u = __shfl_up(incl, d); if (lane >= d) incl += u; }
        if (lane == 63) wtot[wid] = incl;
        __syncthreads();
        int carry = 0;
        for (int w = 0; w < wid; ++w) carry += wtot[w];
        int excl = carry + incl - x;
        if (t < NB_V) { base_v[t] = excl; curb_v[t] = excl; }
        if (t == 0) {
            int tot = 0;
            for (int w = 0; w < 16; ++w) tot += wtot[w];
            base_v[NB_V] = tot; off_v[V_N] = tot;
        }
    }
}

// ---------- passA: partition pairs into bucket-contiguous arrays (ids LDS-staged once) ----------
// pair pack: e-dir (elow 8b << 17) | v (17b);  v-dir (vlow 8b << 16) | e (16b)
__global__ __launch_bounds__(512) void passA_k(const int* __restrict__ v_ids,
                                               const int* __restrict__ e_ids,
                                               int* __restrict__ curb_e, int* __restrict__ curb_v,
                                               u32* __restrict__ pairs_e, u32* __restrict__ pairs_v,
                                               int nnz) {
    __shared__ __align__(16) int ids_e[CHUNK];
    __shared__ __align__(16) int ids_v[CHUNK];
    __shared__ __align__(16) u32 stage[CHUNK];
    __shared__ int cnt[512], runoff[513], delta[512], cnt2[512];
    __shared__ int wtot[8];
    const int t = threadIdx.x, lane = t & 63, wid = t >> 6;
    const int nnz4 = nnz >> 2;
    const int b4 = blockIdx.x * (CHUNK >> 2);

    // stage ids to LDS (single global read pass); invalid filler -1
    #pragma unroll
    for (int u = 0; u < 4; ++u) {
        int k4 = u * 512 + t;
        int i4 = b4 + k4;
        int4 e = { -1, -1, -1, -1 }, v = { -1, -1, -1, -1 };
        if (i4 < nnz4) { e = ((const int4*)e_ids)[i4]; v = ((const int4*)v_ids)[i4]; }
        ((int4*)ids_e)[k4] = e;
        ((int4*)ids_v)[k4] = v;
    }
    __syncthreads();

    for (int dir = 0; dir < 2; ++dir) {
        const int nb = dir ? NB_V : NB_E;
        cnt[t] = 0; cnt2[t] = 0;
        __syncthreads();
        // count
        for (int k = t; k < CHUNK; k += 512) {
            int ee = ids_e[k], vv = ids_v[k];
            if ((unsigned)ee < (unsigned)E_N && (unsigned)vv < (unsigned)V_N) {
                int key = dir ? vv : ee;
                atomicAdd(&cnt[key >> 8], 1);
            }
        }
        __syncthreads();
        // exclusive scan cnt[0..nb)
        int x = (t < nb) ? cnt[t] : 0;
        int incl = x;
        for (int d = 1; d < 64; d <<= 1) { int u = __shfl_up(incl, d); if (lane >= d) incl += u; }
        if (lane == 63) wtot[wid] = incl;
        __syncthreads();
        int carry = 0;
        for (int w = 0; w < wid; ++w) carry += wtot[w];
        int excl = carry + incl - x;
        if (t < nb) runoff[t] = excl;
        if (t == 0) {
            int tot = 0;
            for (int w = 0; w < 8; ++w) tot += wtot[w];
            runoff[nb] = tot;
        }
        __syncthreads();
        const int total = runoff[nb];
        // reserve global runs (one atomic per nonempty bucket)
        if (t < nb && cnt[t] > 0) {
            int r = atomicAdd((dir ? curb_v : curb_e) + t, cnt[t]);
            delta[t] = r - runoff[t];
        }
        __syncthreads();
        // scatter into LDS staging grouped by bucket
        for (int k = t; k < CHUNK; k += 512) {
            int ee = ids_e[k], vv = ids_v[k];
            if ((unsigned)ee < (unsigned)E_N && (unsigned)vv < (unsigned)V_N) {
                int key = dir ? vv : ee;
                int b_ = key >> 8;
                u32 pk_ = dir ? (((u32)(key & 255) << 16) | (u32)ee)
                              : (((u32)(key & 255) << 17) | (u32)vv);
                int idx_ = runoff[b_] + atomicAdd(&cnt2[b_], 1);
                stage[idx_] = pk_;
            }
        }
        __syncthreads();
        // coalesced flush (binary-search bucket of each staged slot)
        u32* pairs = dir ? pairs_v : pairs_e;
        for (int i = t; i < total; i += 512) {
            int lo = 0, hi = nb;
            while (hi - lo > 1) { int mid = (lo + hi) >> 1; if (runoff[mid] <= i) lo = mid; else hi = mid; }
            pairs[i + delta[lo]] = stage[i];
        }
        __syncthreads();
    }
}

// ---------- passB: per-bucket CSR finalize, LDS-staged, coalesced in/out ----------
__global__ __launch_bounds__(256) void passB_k(const u32* __restrict__ pairs_e,
                                               const u32* __restrict__ pairs_v,
                                               const int* __restrict__ base_e,
                                               const int* __restrict__ base_v,
                                               int* __restrict__ off_e, int* __restrict__ off_v,
                                               int* __restrict__ se_src, int* __restrict__ sv_src) {
    __shared__ int cntk[256], curk[256];
    __shared__ u32 buf[CAP_B];
    __shared__ int wtot[4];
    int b = blockIdx.x;
    const u32* pairs; const int* base; int* off; int* outv; int keyN, shift; u32 mask;
    if (b < NB_E) { pairs = pairs_e; base = base_e; off = off_e; outv = se_src; keyN = E_N; shift = 17; mask = 0x1FFFFu; }
    else { b -= NB_E; pairs = pairs_v; base = base_v; off = off_v; outv = sv_src; keyN = V_N; shift = 16; mask = 0xFFFFu; }
    const int lo = base[b], hi = base[b + 1], cnt = hi - lo, k0 = b << 8;
    const int t = threadIdx.x, lane = t & 63, wid = t >> 6;
    cntk[t] = 0;
    __syncthreads();
    for (int i = t; i < cnt; i += 256) { u32 p = pairs[lo + i]; atomicAdd(&cntk[p >> shift], 1); }
    __syncthreads();
    int x = cntk[t];
    int incl = x;
    for (int d = 1; d < 64; d <<= 1) { int u = __shfl_up(incl, d); if (lane >= d) incl += u; }
    if (lane == 63) wtot[wid] = incl;
    __syncthreads();
    int carry = 0;
    for (int w = 0; w < wid; ++w) carry += wtot[w];
    int excl = carry + incl - x;
    if (k0 + t < keyN) off[k0 + t] = lo + excl;
    curk[t] = excl;
    __syncthreads();
    if (cnt <= CAP_B) {
        for (int i = t; i < cnt; i += 256) {
            u32 p = pairs[lo + i];
            int pos = atomicAdd(&curk[p >> shift], 1);
            buf[pos] = p & mask;
        }
        __syncthreads();
        for (int i = t; i < cnt; i += 256) outv[lo + i] = (int)buf[i];
    } else {
        // statistically unreachable fallback (keeps correctness unconditional)
        for (int i = t; i < cnt; i += 256) {
            u32 p = pairs[lo + i];
            int pos = atomicAdd(&curk[p >> shift], 1);
            outv[lo + pos] = (int)(p & mask);
        }
    }
}

// ---------- seg: out[seg][c] = post( sum over segment of F[src][c] )  (1 wave per segment) ----------
// MODE 0 (seg_e): post = id (raw sum, f32). MODE 1 (seg_v): post = relu(x/max(len,1)).
// Lane layout: half = lane>>5 picks row of a pair; c = lane&31 covers channels 4c..4c+3 (uint2).
// One 64-lane uint2 load gathers TWO rows; 8-row unroll keeps 4 gathers in flight.
template<int MODE>
__global__ __launch_bounds__(256) void seg_k(const u16* __restrict__ F,
                                             const int* __restrict__ off,
                                             const int* __restrict__ srcs,
                                             float* __restrict__ out, int N) {
    int seg = blockIdx.x * 4 + (threadIdx.x >> 6);
    if (seg >= N) return;
    const int lane = threadIdx.x & 63;
    const int half = lane >> 5;
    const int c = lane & 31;
    int j0 = off[seg], j1 = off[seg + 1];
    float a0 = 0.f, a1 = 0.f, a2 = 0.f, a3 = 0.f;
    int j = j0;
    for (; j + 8 <= j1; j += 8) {
        int s0 = srcs[j + 0 + half];
        int s1 = srcs[j + 2 + half];
        int s2 = srcs[j + 4 + half];
        int s3 = srcs[j + 6 + half];
        uint2 q0 = ((const uint2*)(F + (size_t)s0 * C_N))[c];
        uint2 q1 = ((const uint2*)(F + (size_t)s1 * C_N))[c];
        uint2 q2 = ((const uint2*)(F + (size_t)s2 * C_N))[c];
        uint2 q3 = ((const uint2*)(F + (size_t)s3 * C_N))[c];
        float l, h;
        unpack2(q0.x, l, h); a0 += l; a1 += h; unpack2(q0.y, l, h); a2 += l; a3 += h;
        unpack2(q1.x, l, h); a0 += l; a1 += h; unpack2(q1.y, l, h); a2 += l; a3 += h;
        unpack2(q2.x, l, h); a0 += l; a1 += h; unpack2(q2.y, l, h); a2 += l; a3 += h;
        unpack2(q3.x, l, h); a0 += l; a1 += h; unpack2(q3.y, l, h); a2 += l; a3 += h;
    }
    for (; j + 2 <= j1; j += 2) {
        int s0 = srcs[j + half];
        uint2 q0 = ((const uint2*)(F + (size_t)s0 * C_N))[c];
        float l, h;
        unpack2(q0.x, l, h); a0 += l; a1 += h; unpack2(q0.y, l, h); a2 += l; a3 += h;
    }
    if (j < j1 && half == 0) {
        int s0 = srcs[j];
        uint2 q0 = ((const uint2*)(F + (size_t)s0 * C_N))[c];
        float l, h;
        unpack2(q0.x, l, h); a0 += l; a1 += h; unpack2(q0.y, l, h); a2 += l; a3 += h;
    }
    a0 += __shfl_xor(a0, 32); a1 += __shfl_xor(a1, 32);
    a2 += __shfl_xor(a2, 32); a3 += __shfl_xor(a3, 32);
    if (half == 0) {
        float4 w;
        if (MODE) {
            float inv = 1.0f / (float)max(j1 - j0, 1);
            w.x = fmaxf(a0 * inv, 0.f); w.y = fmaxf(a1 * inv, 0.f);
            w.z = fmaxf(a2 * inv, 0.f); w.w = fmaxf(a3 * inv, 0.f);
        } else {
            w.x = a0; w.y = a1; w.z = a2; w.w = a3;
        }
        ((float4*)(out + (size_t)seg * C_N))[c] = w;
    }
}

// ---------- launch ----------
extern "C" void kernel_launch(void* const* d_in, const int* in_sizes, int n_in,
                              void* d_out, int out_size, void* d_ws, size_t ws_size,
                              hipStream_t stream) {
    const float* X     = (const float*)d_in[0];
    const float* W_v2e = (const float*)d_in[1];
    const float* b_v2e = (const float*)d_in[2];
    const float* W_e2v = (const float*)d_in[3];
    const float* b_e2v = (const float*)d_in[4];
    const int*   v_ids = (const int*)d_in[5];
    const int*   e_ids = (const int*)d_in[6];
    float* out = (float*)d_out;   // f32 [V][128]

    bool sizesOK = (n_in == 7) && (out_size == 12800000)
        && in_sizes[0] == 12800000 && in_sizes[1] == 16384 && in_sizes[2] == 128
        && in_sizes[3] == 16384 && in_sizes[4] == 128
        && in_sizes[5] == 1600000 && in_sizes[6] == 1600000;
    if (!sizesOK) { flagf_k<<<1, 64, 0, stream>>>(out, 1.0e6f); return; }
    if (ws_size < 28000000) { flagf_k<<<1, 64, 0, stream>>>(out, 2.0e6f); return; }
    const int nnz = in_sizes[5];

    // d_out (51.2 MB) doubles as scratch:
    //   Xp bf16 [V][128] @ 0 (25.6M)               -- written by fusedA (gemm1), read by seg_e
    //   pairs_e u32[nnz] @ 25.6M, pairs_v @ 32M    -- written by passA, dead after passB
    //   Ysum f32 [E][128] @ 25.6M (25.6M)          -- written by seg_e (over dead pairs)
    //   out f32 [V][128] @ 0                       -- final write by seg_v
    u16*   Xp      = (u16*)d_out;
    u32*   pairs_e = (u32*)((char*)d_out + 25600000);
    u32*   pairs_v = pairs_e + nnz;
    float* Ysum    = (float*)((char*)d_out + 25600000);

    // ws layout (bytes):
    char* ws = (char*)d_ws;
    u16* Yp     = (u16*)(ws + 0);                   // bf16 [E][128] (12.8M)
    int* se_src = (int*)(ws + 12800000);            // int[nnz]
    int* sv_src = (int*)(ws + 19200000);            // int[nnz]
    int* gbin   = (int*)(ws + 25600000);            // 587 (+pad to 640)
    int* base_e = (int*)(ws + 25602560);            // 197
    int* base_v = (int*)(ws + 25603584);            // 392
    int* curb_e = (int*)(ws + 25605632);            // 196
    int* curb_v = (int*)(ws + 25606656);            // 391
    int* off_e  = (int*)(ws + 25608704);            // 50001
    int* off_v  = (int*)(ws + 25808768);            // 100001  (ends ~26.2M)

    const int NCH = (nnz + CHUNK - 1) / CHUNK;      // 196

    zero_i4<<<1, 256, 0, stream>>>((int4*)gbin, 152);   // 608 ints >= 587, within pad
    fusedA_k<<<G1B + NCH, 256, 0, stream>>>(X, W_v2e, b_v2e, Xp, v_ids, e_ids, gbin, nnz);
    scanB_k<<<1, 1024, 0, stream>>>(gbin, base_e, base_v, curb_e, curb_v, off_e, off_v);
    passA_k<<<NCH, 512, 0, stream>>>(v_ids, e_ids, curb_e, curb_v, pairs_e, pairs_v, nnz);
    passB_k<<<NBINS, 256, 0, stream>>>(pairs_e, pairs_v, base_e, base_v, off_e, off_v, se_src, sv_src);

    seg_k<0><<<(E_N + 3) / 4, 256, 0, stream>>>(Xp, off_e, se_src, Ysum, E_N);
    gemm_tiled_k<1><<<(E_N + 127) / 128, 256, 0, stream>>>(Ysum, W_e2v, b_e2v, off_e, Yp, E_N);
    seg_k<1><<<(V_N + 3) / 4, 256, 0, stream>>>(Yp, off_v, sv_src, out, V_N);

    (void)ws_size;
}